// Round 2
// baseline (329.273 us; speedup 1.0000x reference)
//
#include <hip/hip_runtime.h>
#include <math.h>

#define B_DIM 8
#define T_DIM 512
#define H_DIM 768
#define NTOK 511       // T - 1
#define NLAY 9         // 13 - LAYER_START
#define LAYER_START 4
#define NPAIR 45       // 9*10/2

// per-batch sum of var_tok — device global so we never touch d_ws
// (zeroed by zero_k every call: same work each launch, graph-capture safe)
__device__ float g_Ssum[B_DIM];

// upper-triangular pair index for lo <= hi in a 9x9 Gram
__device__ __forceinline__ int pidx(int lo, int hi) {
  return lo * 9 - lo * (lo - 1) / 2 + (hi - lo);
}

__global__ void zero_k(float* __restrict__ out) {
  int i = blockIdx.x * 256 + threadIdx.x;
  if (i < B_DIM * H_DIM) out[i] = 0.f;
  if (i < B_DIM) g_Ssum[i] = 0.f;
}

__global__ __launch_bounds__(64, 2) void wk_main(const float* __restrict__ ahs,
                                                 float* __restrict__ acc) {
  const int bt = blockIdx.x;
  const int b = bt / NTOK;
  const int t = bt - b * NTOK;
  const int lane = threadIdx.x;

  __shared__ float sG[NPAIR];

  // ---- load 9 layers x 12 floats (3 x float4 per lane), coalesced 16B/lane ----
  float4 v[NLAY][3];
#pragma unroll
  for (int l = 0; l < NLAY; ++l) {
    const float* base =
        ahs + (((size_t)(l + LAYER_START) * B_DIM + b) * T_DIM + t) * H_DIM;
#pragma unroll
    for (int s = 0; s < 3; ++s) {
      v[l][s] = *reinterpret_cast<const float4*>(base + s * 256 + lane * 4);
    }
  }

  // ---- partial 9x9 Gram: 45 pair dots over this lane's 12 columns ----
  float g[NPAIR];
#pragma unroll
  for (int i = 0; i < NLAY; ++i) {
#pragma unroll
    for (int kk = i; kk < NLAY; ++kk) {
      float s0 = 0.f;
#pragma unroll
      for (int s = 0; s < 3; ++s) {
        s0 += v[i][s].x * v[kk][s].x;
        s0 += v[i][s].y * v[kk][s].y;
        s0 += v[i][s].z * v[kk][s].z;
        s0 += v[i][s].w * v[kk][s].w;
      }
      g[pidx(i, kk)] = s0;
    }
  }

  // ---- butterfly all-reduce across the 64-lane wave ----
#pragma unroll
  for (int off = 32; off > 0; off >>= 1) {
#pragma unroll
    for (int p = 0; p < NPAIR; ++p) g[p] += __shfl_xor(g[p], off, 64);
  }

  // park Gram in LDS so later code can index it dynamically (no scratch spill)
  if (lane == 0) {
#pragma unroll
    for (int p = 0; p < NPAIR; ++p) sG[p] = g[p];
  }
  __syncthreads();

  // ---- per-lane k: window rows + Cholesky (R = upper chol of Gram == QR's R
  //      up to row signs, which provably cancel in align/novelty) ----
  const int k = lane < NLAY ? lane : NLAY - 1;
  const int nl = (k >= 2) ? 2 : 0;
  const int nrr = (NLAY - 1 - k) < 2 ? (NLAY - 1 - k) : 2;
  const int m = nl + nrr + 1;  // 3..5, self row last

  auto rowf = [&](int i) -> int {
    return (i < nl) ? (k - 2 + i) : ((i < nl + nrr) ? (k + 1 + i - nl) : k);
  };
  auto GK = [&](int i, int j) -> float {
    int a = rowf(i), c = rowf(j);
    int lo = a < c ? a : c;
    int hi = a < c ? c : a;
    return sG[lo * 9 - lo * (lo - 1) / 2 + (hi - lo)];
  };

  float R[5][5];
#pragma unroll
  for (int j = 0; j < 5; ++j)
#pragma unroll
    for (int i = 0; i < 5; ++i) R[i][j] = 0.f;

#pragma unroll
  for (int j = 0; j < 5; ++j) {
    if (j < m) {
#pragma unroll
      for (int i = 0; i < 5; ++i) {
        if (i < j) {  // compile-time after unroll
          float s = GK(i, j);
#pragma unroll
          for (int p = 0; p < 4; ++p)
            if (p < i) s -= R[p][i] * R[p][j];
          R[i][j] = s / R[i][i];
        }
      }
      float sjj = GK(j, j);
#pragma unroll
      for (int p = 0; p < 4; ++p)
        if (p < j) sjj -= R[p][j] * R[p][j];
      R[j][j] = sqrtf(fmaxf(sjj, 0.f));
    }
  }

  // r = R[:, m-1]  (select with constant indices; R[:,j>=m] are zero anyway)
  float r[5];
#pragma unroll
  for (int i = 0; i < 5; ++i)
    r[i] = (m == 3) ? R[i][2] : ((m == 4) ? R[i][3] : R[i][4]);

  // column-normalize Rsub = R[:m-1,:m-1], row means
  float rowmean[4] = {0.f, 0.f, 0.f, 0.f};
#pragma unroll
  for (int j = 0; j < 4; ++j) {
    if (j < m - 1) {
      float cn = 0.f;
#pragma unroll
      for (int i = 0; i < 4; ++i)
        if (i <= j) cn += R[i][j] * R[i][j];
      cn = fmaxf(sqrtf(cn), 1e-12f);
      float inv = 1.f / cn;
#pragma unroll
      for (int i = 0; i < 4; ++i)
        if (i < m - 1) rowmean[i] += R[i][j] * inv;
    }
  }

  const float inv_m1 = 1.f / (float)(m - 1);
  float dotv = 0.f, nrm2 = 0.f;
#pragma unroll
  for (int i = 0; i < 4; ++i) {
    if (i < m - 1) {
      dotv += (rowmean[i] * inv_m1) * r[i];
      nrm2 += r[i] * r[i];
    }
  }
  float align_raw = dotv / sqrtf(nrm2);
  float align_v = 1.f / (align_raw * (float)m * 2.f);
  float rlast = (m == 3) ? r[2] : ((m == 4) ? r[3] : r[4]);
  float nov_v = fabsf(rlast) / sqrtf(nrm2 + rlast * rlast);

  // ---- broadcast the 9 (align, nov) from lanes 0..8 to all lanes ----
  float al[NLAY], nv[NLAY];
  float asum = 0.f, nsum = 0.f;
#pragma unroll
  for (int l = 0; l < NLAY; ++l) {
    al[l] = __shfl(align_v, l, 64);
    nv[l] = __shfl(nov_v, l, 64);
    asum += al[l];
    nsum += nv[l];
  }
  float alpha[NLAY];
  float csum = 0.f;
#pragma unroll
  for (int l = 0; l < NLAY; ++l) {
    alpha[l] = al[l] / asum + nv[l] / nsum;
    csum += alpha[l];
  }
  const float inv_csum = 1.f / csum;

  // ---- adjacent-layer cosine sims -> sample variance (ddof=1) ----
  float sims[NLAY - 1];
  float smean = 0.f;
#pragma unroll
  for (int j = 0; j < NLAY - 1; ++j) {
    float num = sG[pidx(j, j + 1)];
    float den = fmaxf(sqrtf(sG[pidx(j, j)]) * sqrtf(sG[pidx(j + 1, j + 1)]), 1e-8f);
    sims[j] = num / den;
    smean += sims[j];
  }
  smean *= (1.f / 8.f);
  float var = 0.f;
#pragma unroll
  for (int j = 0; j < NLAY - 1; ++j) {
    float d = sims[j] - smean;
    var += d * d;
  }
  var *= (1.f / 7.f);

  if (lane == 0) atomicAdd(&g_Ssum[b], var);

  // ---- weighted layer sum, accumulate into out[b, :] ----
  float c[NLAY];
#pragma unroll
  for (int l = 0; l < NLAY; ++l) c[l] = var * alpha[l] * inv_csum;

#pragma unroll
  for (int s = 0; s < 3; ++s) {
    float ox = 0.f, oy = 0.f, oz = 0.f, ow = 0.f;
#pragma unroll
    for (int l = 0; l < NLAY; ++l) {
      ox += c[l] * v[l][s].x;
      oy += c[l] * v[l][s].y;
      oz += c[l] * v[l][s].z;
      ow += c[l] * v[l][s].w;
    }
    float* dst = acc + b * H_DIM + s * 256 + lane * 4;
    atomicAdd(dst + 0, ox);
    atomicAdd(dst + 1, oy);
    atomicAdd(dst + 2, oz);
    atomicAdd(dst + 3, ow);
  }
}

__global__ void fin_k(float* __restrict__ out) {
  int i = blockIdx.x * 256 + threadIdx.x;
  if (i < B_DIM * H_DIM) out[i] = out[i] / g_Ssum[i / H_DIM];
}

extern "C" void kernel_launch(void* const* d_in, const int* in_sizes, int n_in,
                              void* d_out, int out_size, void* d_ws, size_t ws_size,
                              hipStream_t stream) {
  const float* ahs = (const float*)d_in[0];
  // d_in[1] = attention_mask: unused by the reference computation
  float* out = (float*)d_out;
  (void)d_ws; (void)ws_size;  // workspace unused — avoid any assumption on its size

  zero_k<<<dim3(25), dim3(256), 0, stream>>>(out);
  wk_main<<<dim3(B_DIM * NTOK), dim3(64), 0, stream>>>(ahs, out);
  fin_k<<<dim3(24), dim3(256), 0, stream>>>(out);
}

// Round 3
// 269.476 us; speedup vs baseline: 1.2219x; 1.2219x over previous
//
#include <hip/hip_runtime.h>
#include <math.h>

#define B_DIM 8
#define T_DIM 512
#define H_DIM 768
#define NTOK 511       // T - 1
#define NLAY 9         // 13 - LAYER_START
#define LAYER_START 4
#define NPAIR 45       // 9*10/2
#define TCHUNK 128     // ceil(NTOK / 4 tokens-per-block)

// Per-block partial outputs and per-block var sums. Module globals so we never
// depend on d_ws. Every element is overwritten by wk_a before wk_r reads it,
// so 0xAA poisoning / stale state across calls is irrelevant. No atomics.
__device__ float g_part[B_DIM * TCHUNK * H_DIM];  // 3 MB
__device__ float g_varp[B_DIM * TCHUNK];

// upper-triangular pair index for lo <= hi in a 9x9 Gram
__device__ __forceinline__ int pidx(int lo, int hi) {
  return lo * 9 - lo * (lo - 1) / 2 + (hi - lo);
}

// 4 waves per block, one token per wave. grid = (TCHUNK, B_DIM).
__global__ __launch_bounds__(256, 4) void wk_a(const float* __restrict__ ahs) {
  const int chunk = blockIdx.x;
  const int b = blockIdx.y;
  const int wave = threadIdx.x >> 6;
  const int lane = threadIdx.x & 63;
  const int t_raw = chunk * 4 + wave;
  const bool active = (t_raw < NTOK);
  const int t = active ? t_raw : (NTOK - 1);  // clamp: loads stay in bounds

  __shared__ float sG[4][48];          // per-wave Gram park (dynamic indexing)
  __shared__ float lds_out[4][H_DIM];  // per-wave token contribution
  __shared__ float lds_var[4];

  // ---- load 9 layers x 12 floats (3 x float4 per lane), coalesced 16B/lane ----
  float4 v[NLAY][3];
#pragma unroll
  for (int l = 0; l < NLAY; ++l) {
    const float* base =
        ahs + (((size_t)(l + LAYER_START) * B_DIM + b) * T_DIM + t) * H_DIM;
#pragma unroll
    for (int s = 0; s < 3; ++s) {
      v[l][s] = *reinterpret_cast<const float4*>(base + s * 256 + lane * 4);
    }
  }

  // ---- partial 9x9 Gram: 45 pair dots over this lane's 12 columns ----
  float g[NPAIR];
#pragma unroll
  for (int i = 0; i < NLAY; ++i) {
#pragma unroll
    for (int kk = i; kk < NLAY; ++kk) {
      float s0 = 0.f;
#pragma unroll
      for (int s = 0; s < 3; ++s) {
        s0 += v[i][s].x * v[kk][s].x;
        s0 += v[i][s].y * v[kk][s].y;
        s0 += v[i][s].z * v[kk][s].z;
        s0 += v[i][s].w * v[kk][s].w;
      }
      g[pidx(i, kk)] = s0;
    }
  }

  // ---- butterfly all-reduce across the 64-lane wave ----
#pragma unroll
  for (int off = 32; off > 0; off >>= 1) {
#pragma unroll
    for (int p = 0; p < NPAIR; ++p) g[p] += __shfl_xor(g[p], off, 64);
  }

  // park Gram in LDS so later code can index it dynamically (no scratch spill)
  if (lane == 0) {
#pragma unroll
    for (int p = 0; p < NPAIR; ++p) sG[wave][p] = g[p];
  }
  __syncthreads();

  // ---- per-lane k: window rows + Cholesky (R = upper chol of Gram == QR's R
  //      up to row signs, which provably cancel in align/novelty) ----
  const int k = lane < NLAY ? lane : NLAY - 1;
  const int nl = (k >= 2) ? 2 : 0;
  const int nrr = (NLAY - 1 - k) < 2 ? (NLAY - 1 - k) : 2;
  const int m = nl + nrr + 1;  // 3..5, self row last

  auto rowf = [&](int i) -> int {
    return (i < nl) ? (k - 2 + i) : ((i < nl + nrr) ? (k + 1 + i - nl) : k);
  };
  auto GK = [&](int i, int j) -> float {
    int a = rowf(i), c = rowf(j);
    int lo = a < c ? a : c;
    int hi = a < c ? c : a;
    return sG[wave][lo * 9 - lo * (lo - 1) / 2 + (hi - lo)];
  };

  float R[5][5];
#pragma unroll
  for (int j = 0; j < 5; ++j)
#pragma unroll
    for (int i = 0; i < 5; ++i) R[i][j] = 0.f;

#pragma unroll
  for (int j = 0; j < 5; ++j) {
    if (j < m) {
#pragma unroll
      for (int i = 0; i < 5; ++i) {
        if (i < j) {  // compile-time after unroll
          float s = GK(i, j);
#pragma unroll
          for (int p = 0; p < 4; ++p)
            if (p < i) s -= R[p][i] * R[p][j];
          R[i][j] = s / R[i][i];
        }
      }
      float sjj = GK(j, j);
#pragma unroll
      for (int p = 0; p < 4; ++p)
        if (p < j) sjj -= R[p][j] * R[p][j];
      R[j][j] = sqrtf(fmaxf(sjj, 0.f));
    }
  }

  // r = R[:, m-1]
  float r[5];
#pragma unroll
  for (int i = 0; i < 5; ++i)
    r[i] = (m == 3) ? R[i][2] : ((m == 4) ? R[i][3] : R[i][4]);

  // column-normalize Rsub = R[:m-1,:m-1], row means
  float rowmean[4] = {0.f, 0.f, 0.f, 0.f};
#pragma unroll
  for (int j = 0; j < 4; ++j) {
    if (j < m - 1) {
      float cn = 0.f;
#pragma unroll
      for (int i = 0; i < 4; ++i)
        if (i <= j) cn += R[i][j] * R[i][j];
      cn = fmaxf(sqrtf(cn), 1e-12f);
      float inv = 1.f / cn;
#pragma unroll
      for (int i = 0; i < 4; ++i)
        if (i < m - 1) rowmean[i] += R[i][j] * inv;
    }
  }

  const float inv_m1 = 1.f / (float)(m - 1);
  float dotv = 0.f, nrm2 = 0.f;
#pragma unroll
  for (int i = 0; i < 4; ++i) {
    if (i < m - 1) {
      dotv += (rowmean[i] * inv_m1) * r[i];
      nrm2 += r[i] * r[i];
    }
  }
  float align_raw = dotv / sqrtf(nrm2);
  float align_v = 1.f / (align_raw * (float)m * 2.f);
  float rlast = (m == 3) ? r[2] : ((m == 4) ? r[3] : r[4]);
  float nov_v = fabsf(rlast) / sqrtf(nrm2 + rlast * rlast);

  // ---- broadcast the 9 (align, nov) from lanes 0..8 to all lanes ----
  float al[NLAY], nv[NLAY];
  float asum = 0.f, nsum = 0.f;
#pragma unroll
  for (int l = 0; l < NLAY; ++l) {
    al[l] = __shfl(align_v, l, 64);
    nv[l] = __shfl(nov_v, l, 64);
    asum += al[l];
    nsum += nv[l];
  }
  float alpha[NLAY];
  float csum = 0.f;
#pragma unroll
  for (int l = 0; l < NLAY; ++l) {
    alpha[l] = al[l] / asum + nv[l] / nsum;
    csum += alpha[l];
  }
  const float inv_csum = 1.f / csum;

  // ---- adjacent-layer cosine sims -> sample variance (ddof=1) ----
  float sims[NLAY - 1];
  float smean = 0.f;
#pragma unroll
  for (int j = 0; j < NLAY - 1; ++j) {
    float num = sG[wave][pidx(j, j + 1)];
    float den =
        fmaxf(sqrtf(sG[wave][pidx(j, j)]) * sqrtf(sG[wave][pidx(j + 1, j + 1)]),
              1e-8f);
    sims[j] = num / den;
    smean += sims[j];
  }
  smean *= (1.f / 8.f);
  float var = 0.f;
#pragma unroll
  for (int j = 0; j < NLAY - 1; ++j) {
    float d = sims[j] - smean;
    var += d * d;
  }
  var *= (1.f / 7.f);
  if (!active) var = 0.f;  // inactive wave contributes exactly zero

  if (lane == 0) lds_var[wave] = var;

  // ---- weighted layer sum -> this wave's LDS region (no atomics) ----
  float c[NLAY];
#pragma unroll
  for (int l = 0; l < NLAY; ++l) c[l] = var * alpha[l] * inv_csum;

#pragma unroll
  for (int s = 0; s < 3; ++s) {
    float4 o;
    o.x = 0.f; o.y = 0.f; o.z = 0.f; o.w = 0.f;
#pragma unroll
    for (int l = 0; l < NLAY; ++l) {
      o.x += c[l] * v[l][s].x;
      o.y += c[l] * v[l][s].y;
      o.z += c[l] * v[l][s].z;
      o.w += c[l] * v[l][s].w;
    }
    *reinterpret_cast<float4*>(&lds_out[wave][s * 256 + lane * 4]) = o;
  }
  __syncthreads();

  // ---- cross-wave sum, one partial vector + one partial var per block ----
  float* dst = g_part + ((size_t)(b * TCHUNK + chunk)) * H_DIM;
#pragma unroll
  for (int s = 0; s < 3; ++s) {
    int h = s * 256 + threadIdx.x;
    float sum = lds_out[0][h] + lds_out[1][h] + lds_out[2][h] + lds_out[3][h];
    dst[h] = sum;
  }
  if (threadIdx.x == 0) {
    g_varp[b * TCHUNK + chunk] =
        lds_var[0] + lds_var[1] + lds_var[2] + lds_var[3];
  }
}

// grid = (3, B_DIM) x 256 threads: reduce 128 partials, divide by Ssum, write out
__global__ __launch_bounds__(256) void wk_r(float* __restrict__ out) {
  const int b = blockIdx.y;
  const int h = blockIdx.x * 256 + threadIdx.x;

  float acc = 0.f;
#pragma unroll 8
  for (int j = 0; j < TCHUNK; ++j)
    acc += g_part[((size_t)(b * TCHUNK + j)) * H_DIM + h];

  float ssum = 0.f;  // uniform address stream -> scalar loads
#pragma unroll 8
  for (int j = 0; j < TCHUNK; ++j) ssum += g_varp[b * TCHUNK + j];

  out[b * H_DIM + h] = acc / ssum;
}

extern "C" void kernel_launch(void* const* d_in, const int* in_sizes, int n_in,
                              void* d_out, int out_size, void* d_ws, size_t ws_size,
                              hipStream_t stream) {
  const float* ahs = (const float*)d_in[0];
  // d_in[1] = attention_mask: unused by the reference computation
  float* out = (float*)d_out;
  (void)d_ws; (void)ws_size;

  wk_a<<<dim3(TCHUNK, B_DIM), dim3(256), 0, stream>>>(ahs);
  wk_r<<<dim3(3, B_DIM), dim3(256), 0, stream>>>(out);
}

// Round 4
// 236.876 us; speedup vs baseline: 1.3901x; 1.1376x over previous
//
#include <hip/hip_runtime.h>
#include <math.h>

#define B_DIM 8
#define T_DIM 512
#define H_DIM 768
#define NTOK 511       // T - 1
#define NLAY 9         // 13 - LAYER_START
#define LAYER_START 4
#define NPAIR 45       // 9*10/2
#define TCHUNK 128     // ceil(NTOK / 4 tokens-per-block)

// Per-block partial outputs and per-block var sums. Module globals so we never
// depend on d_ws. Every element is overwritten by wk_a before wk_r reads it,
// so 0xAA poisoning / stale state across calls is irrelevant. No atomics.
__device__ float g_part[B_DIM * TCHUNK * H_DIM];  // 3 MB
__device__ float g_varp[B_DIM * TCHUNK];

// upper-triangular pair index for lo <= hi in a 9x9 Gram
__device__ __forceinline__ int pidx(int lo, int hi) {
  return lo * 9 - lo * (lo - 1) / 2 + (hi - lo);
}

// 4 waves per block, one token per wave. grid = (TCHUNK, B_DIM).
// __launch_bounds__(256, 2): cap 256 VGPRs. Peak live set is ~175 VGPRs
// (v[9][3] float4 = 108, g[45], ~20 temps); the (256,4) variant capped at
// 64 VGPRs and spilled ~126 MB/dispatch to scratch (R3: WRITE_SIZE=129 MB).
__global__ __launch_bounds__(256, 2) void wk_a(const float* __restrict__ ahs) {
  const int chunk = blockIdx.x;
  const int b = blockIdx.y;
  const int wave = threadIdx.x >> 6;
  const int lane = threadIdx.x & 63;
  const int t_raw = chunk * 4 + wave;
  const bool active = (t_raw < NTOK);
  const int t = active ? t_raw : (NTOK - 1);  // clamp: loads stay in bounds

  __shared__ float sG[4][48];          // per-wave Gram park (dynamic indexing)
  __shared__ float lds_out[4][H_DIM];  // per-wave token contribution
  __shared__ float lds_var[4];

  // ---- load 9 layers x 12 floats (3 x float4 per lane), coalesced 16B/lane ----
  float4 v[NLAY][3];
#pragma unroll
  for (int l = 0; l < NLAY; ++l) {
    const float* base =
        ahs + (((size_t)(l + LAYER_START) * B_DIM + b) * T_DIM + t) * H_DIM;
#pragma unroll
    for (int s = 0; s < 3; ++s) {
      v[l][s] = *reinterpret_cast<const float4*>(base + s * 256 + lane * 4);
    }
  }

  // ---- partial 9x9 Gram: 45 pair dots over this lane's 12 columns ----
  float g[NPAIR];
#pragma unroll
  for (int i = 0; i < NLAY; ++i) {
#pragma unroll
    for (int kk = i; kk < NLAY; ++kk) {
      float s0 = 0.f;
#pragma unroll
      for (int s = 0; s < 3; ++s) {
        s0 += v[i][s].x * v[kk][s].x;
        s0 += v[i][s].y * v[kk][s].y;
        s0 += v[i][s].z * v[kk][s].z;
        s0 += v[i][s].w * v[kk][s].w;
      }
      g[pidx(i, kk)] = s0;
    }
  }

  // ---- butterfly all-reduce across the 64-lane wave ----
#pragma unroll
  for (int off = 32; off > 0; off >>= 1) {
#pragma unroll
    for (int p = 0; p < NPAIR; ++p) g[p] += __shfl_xor(g[p], off, 64);
  }

  // park Gram in LDS so later code can index it dynamically (no scratch spill)
  if (lane == 0) {
#pragma unroll
    for (int p = 0; p < NPAIR; ++p) sG[wave][p] = g[p];
  }
  __syncthreads();

  // ---- per-lane k: window rows + Cholesky (R = upper chol of Gram == QR's R
  //      up to row signs, which provably cancel in align/novelty) ----
  const int k = lane < NLAY ? lane : NLAY - 1;
  const int nl = (k >= 2) ? 2 : 0;
  const int nrr = (NLAY - 1 - k) < 2 ? (NLAY - 1 - k) : 2;
  const int m = nl + nrr + 1;  // 3..5, self row last

  auto rowf = [&](int i) -> int {
    return (i < nl) ? (k - 2 + i) : ((i < nl + nrr) ? (k + 1 + i - nl) : k);
  };
  auto GK = [&](int i, int j) -> float {
    int a = rowf(i), c = rowf(j);
    int lo = a < c ? a : c;
    int hi = a < c ? c : a;
    return sG[wave][lo * 9 - lo * (lo - 1) / 2 + (hi - lo)];
  };

  float R[5][5];
#pragma unroll
  for (int j = 0; j < 5; ++j)
#pragma unroll
    for (int i = 0; i < 5; ++i) R[i][j] = 0.f;

#pragma unroll
  for (int j = 0; j < 5; ++j) {
    if (j < m) {
#pragma unroll
      for (int i = 0; i < 5; ++i) {
        if (i < j) {  // compile-time after unroll
          float s = GK(i, j);
#pragma unroll
          for (int p = 0; p < 4; ++p)
            if (p < i) s -= R[p][i] * R[p][j];
          R[i][j] = s / R[i][i];
        }
      }
      float sjj = GK(j, j);
#pragma unroll
      for (int p = 0; p < 4; ++p)
        if (p < j) sjj -= R[p][j] * R[p][j];
      R[j][j] = sqrtf(fmaxf(sjj, 0.f));
    }
  }

  // r = R[:, m-1]
  float r[5];
#pragma unroll
  for (int i = 0; i < 5; ++i)
    r[i] = (m == 3) ? R[i][2] : ((m == 4) ? R[i][3] : R[i][4]);

  // column-normalize Rsub = R[:m-1,:m-1], row means
  float rowmean[4] = {0.f, 0.f, 0.f, 0.f};
#pragma unroll
  for (int j = 0; j < 4; ++j) {
    if (j < m - 1) {
      float cn = 0.f;
#pragma unroll
      for (int i = 0; i < 4; ++i)
        if (i <= j) cn += R[i][j] * R[i][j];
      cn = fmaxf(sqrtf(cn), 1e-12f);
      float inv = 1.f / cn;
#pragma unroll
      for (int i = 0; i < 4; ++i)
        if (i < m - 1) rowmean[i] += R[i][j] * inv;
    }
  }

  const float inv_m1 = 1.f / (float)(m - 1);
  float dotv = 0.f, nrm2 = 0.f;
#pragma unroll
  for (int i = 0; i < 4; ++i) {
    if (i < m - 1) {
      dotv += (rowmean[i] * inv_m1) * r[i];
      nrm2 += r[i] * r[i];
    }
  }
  float align_raw = dotv / sqrtf(nrm2);
  float align_v = 1.f / (align_raw * (float)m * 2.f);
  float rlast = (m == 3) ? r[2] : ((m == 4) ? r[3] : r[4]);
  float nov_v = fabsf(rlast) / sqrtf(nrm2 + rlast * rlast);

  // ---- broadcast the 9 (align, nov) from lanes 0..8 to all lanes ----
  float al[NLAY], nv[NLAY];
  float asum = 0.f, nsum = 0.f;
#pragma unroll
  for (int l = 0; l < NLAY; ++l) {
    al[l] = __shfl(align_v, l, 64);
    nv[l] = __shfl(nov_v, l, 64);
    asum += al[l];
    nsum += nv[l];
  }
  float alpha[NLAY];
  float csum = 0.f;
#pragma unroll
  for (int l = 0; l < NLAY; ++l) {
    alpha[l] = al[l] / asum + nv[l] / nsum;
    csum += alpha[l];
  }
  const float inv_csum = 1.f / csum;

  // ---- adjacent-layer cosine sims -> sample variance (ddof=1) ----
  float sims[NLAY - 1];
  float smean = 0.f;
#pragma unroll
  for (int j = 0; j < NLAY - 1; ++j) {
    float num = sG[wave][pidx(j, j + 1)];
    float den =
        fmaxf(sqrtf(sG[wave][pidx(j, j)]) * sqrtf(sG[wave][pidx(j + 1, j + 1)]),
              1e-8f);
    sims[j] = num / den;
    smean += sims[j];
  }
  smean *= (1.f / 8.f);
  float var = 0.f;
#pragma unroll
  for (int j = 0; j < NLAY - 1; ++j) {
    float d = sims[j] - smean;
    var += d * d;
  }
  var *= (1.f / 7.f);
  if (!active) var = 0.f;  // inactive wave contributes exactly zero

  if (lane == 0) lds_var[wave] = var;

  // ---- weighted layer sum -> this wave's LDS region (no atomics) ----
  float c[NLAY];
#pragma unroll
  for (int l = 0; l < NLAY; ++l) c[l] = var * alpha[l] * inv_csum;

#pragma unroll
  for (int s = 0; s < 3; ++s) {
    float4 o;
    o.x = 0.f; o.y = 0.f; o.z = 0.f; o.w = 0.f;
#pragma unroll
    for (int l = 0; l < NLAY; ++l) {
      o.x += c[l] * v[l][s].x;
      o.y += c[l] * v[l][s].y;
      o.z += c[l] * v[l][s].z;
      o.w += c[l] * v[l][s].w;
    }
    *reinterpret_cast<float4*>(&lds_out[wave][s * 256 + lane * 4]) = o;
  }
  __syncthreads();

  // ---- cross-wave sum, one partial vector + one partial var per block ----
  float* dst = g_part + ((size_t)(b * TCHUNK + chunk)) * H_DIM;
#pragma unroll
  for (int s = 0; s < 3; ++s) {
    int h = s * 256 + threadIdx.x;
    float sum = lds_out[0][h] + lds_out[1][h] + lds_out[2][h] + lds_out[3][h];
    dst[h] = sum;
  }
  if (threadIdx.x == 0) {
    g_varp[b * TCHUNK + chunk] =
        lds_var[0] + lds_var[1] + lds_var[2] + lds_var[3];
  }
}

// grid = (3, B_DIM) x 256 threads: reduce 128 partials, divide by Ssum, write out
__global__ __launch_bounds__(256) void wk_r(float* __restrict__ out) {
  const int b = blockIdx.y;
  const int h = blockIdx.x * 256 + threadIdx.x;

  float acc = 0.f;
#pragma unroll 8
  for (int j = 0; j < TCHUNK; ++j)
    acc += g_part[((size_t)(b * TCHUNK + j)) * H_DIM + h];

  float ssum = 0.f;  // uniform address stream -> scalar loads
#pragma unroll 8
  for (int j = 0; j < TCHUNK; ++j) ssum += g_varp[b * TCHUNK + j];

  out[b * H_DIM + h] = acc / ssum;
}

extern "C" void kernel_launch(void* const* d_in, const int* in_sizes, int n_in,
                              void* d_out, int out_size, void* d_ws, size_t ws_size,
                              hipStream_t stream) {
  const float* ahs = (const float*)d_in[0];
  // d_in[1] = attention_mask: unused by the reference computation
  float* out = (float*)d_out;
  (void)d_ws; (void)ws_size;

  wk_a<<<dim3(TCHUNK, B_DIM), dim3(256), 0, stream>>>(ahs);
  wk_r<<<dim3(3, B_DIM), dim3(256), 0, stream>>>(out);
}